// Round 7
// baseline (580.969 us; speedup 1.0000x reference)
//
#include <hip/hip_runtime.h>
#include <hip/hip_bf16.h>

#define HH 224
#define WW 224

// d_out layout (floats): feats[32*128] | final_boxes[32*100*4] | final_scores[32*100] | keep[32*100]
#define OUT_FEATS  0
#define OUT_BOXES  4096
#define OUT_SCORES 16896
#define OUT_KEEP   20096

typedef __attribute__((ext_vector_type(8))) short short8;
typedef __attribute__((ext_vector_type(4))) float f32x4;
typedef __attribute__((ext_vector_type(4))) unsigned int u32x4;
typedef __attribute__((ext_vector_type(2))) unsigned int u32x2;

static __device__ __forceinline__ unsigned short f2bf(float f) {
    __hip_bfloat16 h = __float2bfloat16(f);
    return *(unsigned short*)&h;
}

static __device__ __forceinline__ void gload_lds16(const void* g, void* l) {
    __builtin_amdgcn_global_load_lds(
        (const __attribute__((address_space(1))) unsigned int*)g,
        (__attribute__((address_space(3))) unsigned int*)l, 16, 0, 0);
}

// ---------------- w2 (128,64,3,3) fp32 -> bf16 w2t[tap][h][lq][oc][8]  (ic = h*32+lq*8+e) ----------------
__global__ void w2_convert(const float* __restrict__ w2, unsigned short* __restrict__ w2t)
{
    int t = blockIdx.x * 256 + threadIdx.x;
    if (t >= 9 * 128 * 64) return;
    int e   = t & 7;
    int oc  = (t >> 3) & 127;
    int lq  = (t >> 10) & 3;
    int h   = (t >> 12) & 1;
    int tap = t >> 13;
    int ic  = h * 32 + lq * 8 + e;
    w2t[t] = f2bf(w2[(oc * 64 + ic) * 9 + tap]);
}

// ---------------- w1 (64,3,3,3) fp32 -> bf16 [oc][k32], k=ic*9+dy*3+dx, pad 27..31=0 ----------------
__global__ void w1_convert(const float* __restrict__ w1, unsigned short* __restrict__ w1bf)
{
    int t = blockIdx.x * 256 + threadIdx.x;
    if (t >= 64 * 32) return;
    int oc = t >> 5, k = t & 31;
    unsigned short v = 0;
    if (k < 27) v = f2bf(w1[oc * 27 + k]);   // w1 is [oc][ic][dy][dx] = [oc][k] contiguous
    w1bf[t] = v;
}

// ---------------- conv1 MFMA: (8,3,224,224) fp32 -> relu -> h1 slice NHWC bf16 ----------------
__global__ __launch_bounds__(256) void conv1_kernel(const float* __restrict__ x,
                                                    const unsigned short* __restrict__ w1bf,
                                                    const float* __restrict__ b1,
                                                    unsigned short* __restrict__ h1)
{
    const int x0 = blockIdx.x * 16, y0 = blockIdx.y * 16, b = blockIdx.z;
    const int tid = threadIdx.x;
    const int w = tid >> 6, lane = tid & 63;
    const int l15 = lane & 15, lq = lane >> 4;

    __shared__ float patch[1280];   // [ic][18][18] = 972 used; tail zeroed (k>=27 reads land there)

    for (int e = tid; e < 1280; e += 256) {
        float v = 0.f;
        if (e < 972) {
            int ic = e / 324; int rem = e - ic * 324;
            int r = rem / 18, c = rem - r * 18;
            int gy = y0 + r - 1, gx = x0 + c - 1;
            if (gy >= 0 && gy < HH && gx >= 0 && gx < WW)
                v = x[((b * 3 + ic) * HH + gy) * WW + gx];
        }
        patch[e] = v;
    }

    short8 aw[4];
#pragma unroll
    for (int f = 0; f < 4; f++)
        aw[f] = *(const short8*)(w1bf + (f * 16 + l15) * 32 + lq * 8);
    float bias[4][4];
#pragma unroll
    for (int f = 0; f < 4; f++)
#pragma unroll
        for (int j = 0; j < 4; j++)
            bias[f][j] = b1[f * 16 + lq * 4 + j];

    int koff[8];
#pragma unroll
    for (int j = 0; j < 8; j++) {
        int k = lq * 8 + j;
        int ic = (k >= 18) ? 2 : (k >= 9 ? 1 : 0);
        int t = k - ic * 9;
        int dy = (t >= 6) ? 2 : (t >= 3 ? 1 : 0);
        int dx = t - dy * 3;
        koff[j] = (k < 27) ? ((ic * 18 + dy) * 18 + dx) * 4 : 3888;
    }
    __syncthreads();

    const char* pb = (const char*)patch;

#pragma unroll
    for (int g = 0; g < 4; g++) {
        const int row = w * 4 + g;
        const int rofs = row * 72 + l15 * 4;
        float pv[8];
#pragma unroll
        for (int j = 0; j < 8; j++)
            pv[j] = *(const float*)(pb + (koff[j] + rofs));
        short8 bp;
        unsigned int* bpu = (unsigned int*)&bp;
#pragma unroll
        for (int jj = 0; jj < 4; jj++)
            bpu[jj] = (unsigned int)f2bf(pv[2 * jj]) | ((unsigned int)f2bf(pv[2 * jj + 1]) << 16);

        const int gy = y0 + row, gx = x0 + l15;
        unsigned short* dst = h1 + (((size_t)b * HH + gy) * WW + gx) * 64 + lq * 4;
#pragma unroll
        for (int f = 0; f < 4; f++) {
            f32x4 c = __builtin_amdgcn_mfma_f32_16x16x32_bf16(aw[f], bp,
                        (f32x4){0.f, 0.f, 0.f, 0.f}, 0, 0, 0);
            float v0 = fmaxf(c[0] + bias[f][0], 0.f);
            float v1 = fmaxf(c[1] + bias[f][1], 0.f);
            float v2 = fmaxf(c[2] + bias[f][2], 0.f);
            float v3 = fmaxf(c[3] + bias[f][3], 0.f);
            u32x2 pk;
            pk.x = (unsigned int)f2bf(v0) | ((unsigned int)f2bf(v1) << 16);
            pk.y = (unsigned int)f2bf(v2) | ((unsigned int)f2bf(v3) << 16);
            *(u32x2*)(dst + f * 16) = pk;
        }
    }
}

// ---------------- conv2 MFMA implicit GEMM + fused relu/mean partials ----------------
// 512 thr = 8 waves. Tile: 32 rows x 16 cols px x 128 oc. Wave (wm 0..3, wn 0..1):
// 128 px (rows wm*8..+8, M=8) x 64 oc (N=4), acc=128 regs (R3-proven no-spill shape).
// LDS: full halo (34x18x64ic, 76.5KB) + all-9-tap weights for ONE ic-half (72KB) = 148.5KB.
// K-loop: 2 ic-halves x 9 taps; inside a half: ZERO barriers, ZERO global ops.
// launch_bounds(512, 1): LDS already caps at 1 block/CU; min-blocks=1 keeps the
// 256-reg/wave budget (2 waves/SIMD). (512,2) capped regs at 128 -> acc spill (R4-R6).
__global__ __launch_bounds__(512, 1) void conv2_kernel(const unsigned short* __restrict__ h1,
                                                       const unsigned short* __restrict__ w2t,
                                                       const float* __restrict__ b2,
                                                       float* __restrict__ partial,
                                                       int bglobal_base)
{
    const int xt = blockIdx.x, yt = blockIdx.y, bl = blockIdx.z;
    const int x0 = xt * 16, y0 = yt * 32;
    const int tid = threadIdx.x;
    const int w = tid >> 6, lane = tid & 63;
    const int wm = w >> 1;          // 0..3 : px rows [wm*8, wm*8+8)
    const int wn = w & 1;           // 0..1 : oc [wn*64, wn*64+64)
    const int l15 = lane & 15, lq = lane >> 4;

    __shared__ short halo[612 * 64];        // 34x18 pos x 64 ic, XOR-swizzled, 78336 B
    __shared__ short wlds[9 * 4 * 128 * 8]; // [tap][lq][oc][8ic] linear, 73728 B

    // ---- stage weights half h=0 via global_load_lds (linear dest) ----
#pragma unroll
    for (int k = 0; k < 9; k++) {
        int q = k * 8 + w;                   // 0..71 KB-chunk id; tap = q>>3, sub = q&7
        int tap = q >> 3, sub = q & 7;
        gload_lds16((const char*)w2t + tap * 16384 + 0 * 8192 + sub * 1024 + lane * 16,
                    (char*)wlds + q * 1024);
    }

    // ---- stage full halo (reg-staged, swizzled ds_write; zero-padded borders) ----
    const unsigned short* hb = h1 + (size_t)bl * HH * WW * 64;
    for (int i = tid; i < 4896; i += 512) {
        int pos = i >> 3, q = i & 7;
        int row = pos / 18, col = pos - row * 18;
        int gy = y0 + row - 1, gx = x0 + col - 1;
        u32x4 v = {0, 0, 0, 0};
        if (gy >= 0 && gy < HH && gx >= 0 && gx < WW)
            v = *(const u32x4*)(hb + ((gy * WW + gx) * 64 + q * 8));
        int byte = (pos * 128 + q * 16) ^ ((pos & 7) << 4);
        *(u32x4*)((char*)halo + byte) = v;
    }
    __syncthreads();

    f32x4 acc[8][4];
#pragma unroll
    for (int mf = 0; mf < 8; mf++)
#pragma unroll
        for (int nf = 0; nf < 4; nf++)
            acc[mf][nf] = (f32x4){0.f, 0.f, 0.f, 0.f};

#pragma unroll
    for (int h = 0; h < 2; h++) {
        if (h == 1) {
            __syncthreads();   // all h0 B-reads complete
#pragma unroll
            for (int k = 0; k < 9; k++) {
                int q = k * 8 + w;
                int tap = q >> 3, sub = q & 7;
                gload_lds16((const char*)w2t + tap * 16384 + 8192 + sub * 1024 + lane * 16,
                            (char*)wlds + q * 1024);
            }
            __syncthreads();   // drains vmcnt; publishes h1 weights
        }
#pragma unroll
        for (int t = 0; t < 9; ++t) {
            const int dy = t / 3, dx = t % 3;
            short8 bfr[4];
#pragma unroll
            for (int nf = 0; nf < 4; nf++)
                bfr[nf] = *(const short8*)((const char*)wlds +
                            t * 8192 + lq * 2048 + (wn * 64 + nf * 16 + l15) * 16);
#pragma unroll
            for (int mf = 0; mf < 8; mf++) {
                int pos = (wm * 8 + mf + dy) * 18 + (l15 + dx);
                int byte = (pos * 128 + h * 64 + lq * 16) ^ ((pos & 7) << 4);
                short8 a = *(const short8*)((const char*)halo + byte);
#pragma unroll
                for (int nf = 0; nf < 4; nf++)
                    acc[mf][nf] = __builtin_amdgcn_mfma_f32_16x16x32_bf16(a, bfr[nf], acc[mf][nf], 0, 0, 0);
            }
        }
    }

    // epilogue: bias + relu + sum over wave's 128 px; C: col(oc)=l15, row(px)=lq*4+j
    float s[4];
#pragma unroll
    for (int nf = 0; nf < 4; nf++) {
        float bias = b2[wn * 64 + nf * 16 + l15];
        float v = 0.f;
#pragma unroll
        for (int mf = 0; mf < 8; mf++)
#pragma unroll
            for (int j = 0; j < 4; j++)
                v += fmaxf(acc[mf][nf][j] + bias, 0.f);
        v += __shfl_xor(v, 16, 64);
        v += __shfl_xor(v, 32, 64);
        s[nf] = v;
    }

    __syncthreads();               // all halo reads complete before reuse
    float* red = (float*)halo;     // [wm 4][wn 2][nf 4][16] = 512 floats
    if (lq == 0) {
#pragma unroll
        for (int nf = 0; nf < 4; nf++)
            red[((wm * 2 + wn) * 4 + nf) * 16 + l15] = s[nf];
    }
    __syncthreads();
    if (tid < 128) {
        int oc = tid;
        int wn2 = oc >> 6, nf2 = (oc >> 4) & 3, c16 = oc & 15;
        float tot = 0.f;
#pragma unroll
        for (int wm2 = 0; wm2 < 4; wm2++)
            tot += red[((wm2 * 2 + wn2) * 4 + nf2) * 16 + c16];
        int bg = bglobal_base + bl;
        int tile = yt * 14 + xt;
        partial[((size_t)bg * 128 + oc) * 98 + tile] = tot;
    }
}

// ---------------- feats: sum 98 tile-partials -> mean ----------------
__global__ void feats_reduce(const float* __restrict__ partial, float* __restrict__ out)
{
    int t = blockIdx.x;           // 0..4095 = b*128+oc
    int lane = threadIdx.x;       // 64
    float s = 0.f;
    for (int k = lane; k < 98; k += 64) s += partial[(size_t)t * 98 + k];
#pragma unroll
    for (int m = 32; m >= 1; m >>= 1) s += __shfl_xor(s, m, 64);
    if (lane == 0) out[t] = s * (1.f / 50176.f);
}

// ---------------- NMS: one block per batch (exact reference semantics) ----------------
__global__ __launch_bounds__(128) void nms_kernel(const float* __restrict__ boxes,
                                                  const float* __restrict__ scores,
                                                  float* __restrict__ out)
{
    const int b = blockIdx.x;
    const int tid = threadIdx.x;
    __shared__ float rs[100];
    __shared__ float bx1[100], by1[100], bx2[100], by2[100];
    __shared__ float ss[100], sx1[100], sy1[100], sx2[100], sy2[100], sarea[100];
    __shared__ int keep_s[100];

    if (tid < 100) {
        rs[tid] = scores[b * 100 + tid];
        bx1[tid] = boxes[(b * 100 + tid) * 4 + 0];
        by1[tid] = boxes[(b * 100 + tid) * 4 + 1];
        bx2[tid] = boxes[(b * 100 + tid) * 4 + 2];
        by2[tid] = boxes[(b * 100 + tid) * 4 + 3];
    }
    __syncthreads();
    if (tid < 100) {
        float s = rs[tid];
        int r = 0;
        for (int j = 0; j < 100; j++) {
            float sj = rs[j];
            r += (sj > s) || (sj == s && j < tid);  // stable descending rank
        }
        ss[r] = s; sx1[r] = bx1[tid]; sy1[r] = by1[tid];
        sx2[r] = bx2[tid]; sy2[r] = by2[tid];
        keep_s[tid] = 1;
    }
    __syncthreads();
    if (tid < 100)
        sarea[tid] = fmaxf(sx2[tid] - sx1[tid], 0.f) * fmaxf(sy2[tid] - sy1[tid], 0.f);
    __syncthreads();

    for (int i = 0; i < 99; i++) {
        if (keep_s[i] && tid > i && tid < 100) {
            float xx1 = fmaxf(sx1[i], sx1[tid]);
            float yy1 = fmaxf(sy1[i], sy1[tid]);
            float xx2 = fminf(sx2[i], sx2[tid]);
            float yy2 = fminf(sy2[i], sy2[tid]);
            float inter = fmaxf(xx2 - xx1, 0.f) * fmaxf(yy2 - yy1, 0.f);
            float iou = inter / (sarea[i] + sarea[tid] - inter + 1e-9f);
            if (iou > 0.5f) keep_s[tid] = 0;
        }
        __syncthreads();
    }

    if (tid < 100) {
        int k = keep_s[tid];
        int gi = b * 100 + tid;
        out[OUT_BOXES + gi * 4 + 0] = k ? sx1[tid] : 0.f;
        out[OUT_BOXES + gi * 4 + 1] = k ? sy1[tid] : 0.f;
        out[OUT_BOXES + gi * 4 + 2] = k ? sx2[tid] : 0.f;
        out[OUT_BOXES + gi * 4 + 3] = k ? sy2[tid] : 0.f;
        out[OUT_SCORES + gi] = k ? ss[tid] : 0.f;
        out[OUT_KEEP + gi] = k ? 1.f : 0.f;
    }
}

extern "C" void kernel_launch(void* const* d_in, const int* in_sizes, int n_in,
                              void* d_out, int out_size, void* d_ws, size_t ws_size,
                              hipStream_t stream)
{
    const float* x      = (const float*)d_in[0];
    const float* boxes  = (const float*)d_in[1];
    const float* scores = (const float*)d_in[2];
    const float* w1     = (const float*)d_in[3];
    const float* b1     = (const float*)d_in[4];
    const float* w2     = (const float*)d_in[5];
    const float* b2     = (const float*)d_in[6];
    float* out = (float*)d_out;

    // ws: h1 slice (8 batches NHWC bf16, 51.38 MB) | w2t (147 KB) | w1bf (4 KB) | partial (1.6 MB)
    char* wsb = (char*)d_ws;
    unsigned short* h1   = (unsigned short*)wsb;
    unsigned short* w2t  = (unsigned short*)(wsb + (size_t)8 * 224 * 224 * 64 * 2);
    unsigned short* w1bf = (unsigned short*)(wsb + (size_t)8 * 224 * 224 * 64 * 2 + 9 * 128 * 64 * 2);
    float*          partial = (float*)(wsb + (size_t)8 * 224 * 224 * 64 * 2 + 9 * 128 * 64 * 2 + 64 * 32 * 2);

    w2_convert<<<(9 * 128 * 64 + 255) / 256, 256, 0, stream>>>(w2, w2t);
    w1_convert<<<8, 256, 0, stream>>>(w1, w1bf);

    for (int s = 0; s < 4; s++) {
        const float* xs = x + (size_t)s * 8 * 3 * HH * WW;
        conv1_kernel<<<dim3(14, 14, 8), 256, 0, stream>>>(xs, w1bf, b1, h1);
        conv2_kernel<<<dim3(14, 7, 8), 512, 0, stream>>>(h1, w2t, b2, partial, s * 8);
    }

    feats_reduce<<<4096, 64, 0, stream>>>(partial, out + OUT_FEATS);
    nms_kernel<<<32, 128, 0, stream>>>(boxes, scores, out);
}

// Round 8
// 389.890 us; speedup vs baseline: 1.4901x; 1.4901x over previous
//
#include <hip/hip_runtime.h>
#include <hip/hip_bf16.h>

#define HH 224
#define WW 224

// d_out layout (floats): feats[32*128] | final_boxes[32*100*4] | final_scores[32*100] | keep[32*100]
#define OUT_FEATS  0
#define OUT_BOXES  4096
#define OUT_SCORES 16896
#define OUT_KEEP   20096

typedef __attribute__((ext_vector_type(8))) short short8;
typedef __attribute__((ext_vector_type(4))) float f32x4;
typedef __attribute__((ext_vector_type(4))) unsigned int u32x4;
typedef __attribute__((ext_vector_type(2))) unsigned int u32x2;

static __device__ __forceinline__ unsigned short f2bf(float f) {
    __hip_bfloat16 h = __float2bfloat16(f);
    return *(unsigned short*)&h;
}

static __device__ __forceinline__ void gload_lds16(const void* g, void* l) {
    __builtin_amdgcn_global_load_lds(
        (const __attribute__((address_space(1))) unsigned int*)g,
        (__attribute__((address_space(3))) unsigned int*)l, 16, 0, 0);
}

// ---------------- w2 (128,64,3,3) fp32 -> bf16 [tap][oc][ic] ----------------
__global__ void w2_convert(const float* __restrict__ w2, unsigned short* __restrict__ w2bf)
{
    int t = blockIdx.x * 256 + threadIdx.x;
    if (t >= 9 * 128 * 64) return;
    int tap = t >> 13;
    int rem = t & 8191;
    int oc = rem >> 6, ic = rem & 63;
    w2bf[t] = f2bf(w2[(oc * 64 + ic) * 9 + tap]);
}

// ---------------- w1 (64,3,3,3) fp32 -> bf16 [oc][k32], k=ic*9+dy*3+dx, pad 27..31=0 ----------------
__global__ void w1_convert(const float* __restrict__ w1, unsigned short* __restrict__ w1bf)
{
    int t = blockIdx.x * 256 + threadIdx.x;
    if (t >= 64 * 32) return;
    int oc = t >> 5, k = t & 31;
    unsigned short v = 0;
    if (k < 27) v = f2bf(w1[oc * 27 + k]);
    w1bf[t] = v;
}

// ---------------- conv1 MFMA: (8,3,224,224) fp32 -> relu -> h1 slice NHWC bf16 ----------------
__global__ __launch_bounds__(256) void conv1_kernel(const float* __restrict__ x,
                                                    const unsigned short* __restrict__ w1bf,
                                                    const float* __restrict__ b1,
                                                    unsigned short* __restrict__ h1)
{
    const int x0 = blockIdx.x * 16, y0 = blockIdx.y * 16, b = blockIdx.z;
    const int tid = threadIdx.x;
    const int w = tid >> 6, lane = tid & 63;
    const int l15 = lane & 15, lq = lane >> 4;

    __shared__ float patch[1280];   // [ic][18][18] = 972 used; tail zeroed

    for (int e = tid; e < 1280; e += 256) {
        float v = 0.f;
        if (e < 972) {
            int ic = e / 324; int rem = e - ic * 324;
            int r = rem / 18, c = rem - r * 18;
            int gy = y0 + r - 1, gx = x0 + c - 1;
            if (gy >= 0 && gy < HH && gx >= 0 && gx < WW)
                v = x[((b * 3 + ic) * HH + gy) * WW + gx];
        }
        patch[e] = v;
    }

    short8 aw[4];
#pragma unroll
    for (int f = 0; f < 4; f++)
        aw[f] = *(const short8*)(w1bf + (f * 16 + l15) * 32 + lq * 8);
    float bias[4][4];
#pragma unroll
    for (int f = 0; f < 4; f++)
#pragma unroll
        for (int j = 0; j < 4; j++)
            bias[f][j] = b1[f * 16 + lq * 4 + j];

    int koff[8];
#pragma unroll
    for (int j = 0; j < 8; j++) {
        int k = lq * 8 + j;
        int ic = (k >= 18) ? 2 : (k >= 9 ? 1 : 0);
        int t = k - ic * 9;
        int dy = (t >= 6) ? 2 : (t >= 3 ? 1 : 0);
        int dx = t - dy * 3;
        koff[j] = (k < 27) ? ((ic * 18 + dy) * 18 + dx) * 4 : 3888;
    }
    __syncthreads();

    const char* pb = (const char*)patch;

#pragma unroll
    for (int g = 0; g < 4; g++) {
        const int row = w * 4 + g;
        const int rofs = row * 72 + l15 * 4;
        float pv[8];
#pragma unroll
        for (int j = 0; j < 8; j++)
            pv[j] = *(const float*)(pb + (koff[j] + rofs));
        short8 bp;
        unsigned int* bpu = (unsigned int*)&bp;
#pragma unroll
        for (int jj = 0; jj < 4; jj++)
            bpu[jj] = (unsigned int)f2bf(pv[2 * jj]) | ((unsigned int)f2bf(pv[2 * jj + 1]) << 16);

        const int gy = y0 + row, gx = x0 + l15;
        unsigned short* dst = h1 + (((size_t)b * HH + gy) * WW + gx) * 64 + lq * 4;
#pragma unroll
        for (int f = 0; f < 4; f++) {
            f32x4 c = __builtin_amdgcn_mfma_f32_16x16x32_bf16(aw[f], bp,
                        (f32x4){0.f, 0.f, 0.f, 0.f}, 0, 0, 0);
            float v0 = fmaxf(c[0] + bias[f][0], 0.f);
            float v1 = fmaxf(c[1] + bias[f][1], 0.f);
            float v2 = fmaxf(c[2] + bias[f][2], 0.f);
            float v3 = fmaxf(c[3] + bias[f][3], 0.f);
            u32x2 pk;
            pk.x = (unsigned int)f2bf(v0) | ((unsigned int)f2bf(v1) << 16);
            pk.y = (unsigned int)f2bf(v2) | ((unsigned int)f2bf(v3) << 16);
            *(u32x2*)(dst + f * 16) = pk;
        }
    }
}

// ======== conv2 VARIANT A: proven R2-proposal (72.7us). 256 thr, 4 waves, M8N4. ========
__global__ __launch_bounds__(256, 2) void conv2_kernelA(const unsigned short* __restrict__ h1,
                                                        const unsigned short* __restrict__ w2bf,
                                                        const float* __restrict__ b2,
                                                        float* __restrict__ partial,
                                                        int bglobal_base)
{
    const int xt = blockIdx.x, yt = blockIdx.y, bl = blockIdx.z;
    const int x0 = xt * 16, y0 = yt * 16;
    const int tid = threadIdx.x;
    const int w = tid >> 6, lane = tid & 63;
    const int wm = w >> 1, wn = w & 1;
    const int l15 = lane & 15, lq = lane >> 4;

    __shared__ short halo[324 * 64];       // 18x18 pos x 64 ic, XOR-swizzled, 41472 B
    __shared__ short wlds[2][128 * 64];    // per-tap weights dbuf, XOR-swizzled, 2x16384 B

    const unsigned short* hb = h1 + (size_t)bl * HH * WW * 64;

#pragma unroll
    for (int it = 0; it < 4; ++it) {
        int cbase = it * 256 + w * 64;
        int c = cbase + lane;
        int src = (c * 16) ^ (((c >> 3) & 7) << 4);
        gload_lds16((const char*)w2bf + src, (char*)&wlds[0][0] + cbase * 16);
    }

    for (int i = tid; i < 2592; i += 256) {
        int pos = i >> 3, q = i & 7;
        int row = pos / 18, col = pos - row * 18;
        int gy = y0 + row - 1, gx = x0 + col - 1;
        u32x4 v = {0, 0, 0, 0};
        if (gy >= 0 && gy < HH && gx >= 0 && gx < WW)
            v = *(const u32x4*)(hb + ((gy * WW + gx) * 64 + q * 8));
        int byte = (pos * 128 + q * 16) ^ ((pos & 7) << 4);
        *(u32x4*)((char*)halo + byte) = v;
    }
    __syncthreads();

    f32x4 acc[8][4];
#pragma unroll
    for (int mf = 0; mf < 8; mf++)
#pragma unroll
        for (int nf = 0; nf < 4; nf++)
            acc[mf][nf] = (f32x4){0.f, 0.f, 0.f, 0.f};

#pragma unroll
    for (int t = 0; t < 9; ++t) {
        if (t < 8) {
#pragma unroll
            for (int it = 0; it < 4; ++it) {
                int cbase = it * 256 + w * 64;
                int c = cbase + lane;
                int src = (c * 16) ^ (((c >> 3) & 7) << 4);
                gload_lds16((const char*)w2bf + (t + 1) * 16384 + src,
                            (char*)&wlds[(t + 1) & 1][0] + cbase * 16);
            }
        }
        const int dy = t / 3, dx = t % 3;
        const char* wbuf = (const char*)&wlds[t & 1][0];

#pragma unroll
        for (int kk = 0; kk < 2; kk++) {
            short8 bfr[4];
#pragma unroll
            for (int nf = 0; nf < 4; nf++) {
                int oc = wn * 64 + nf * 16 + l15;
                int byte = (oc * 128 + kk * 64 + lq * 16) ^ ((oc & 7) << 4);
                bfr[nf] = *(const short8*)(wbuf + byte);
            }
            short8 a[8];
#pragma unroll
            for (int mf = 0; mf < 8; mf++) {
                int pos = (wm * 8 + mf + dy) * 18 + (l15 + dx);
                int byte = (pos * 128 + kk * 64 + lq * 16) ^ ((pos & 7) << 4);
                a[mf] = *(const short8*)((const char*)halo + byte);
            }
#pragma unroll
            for (int mf = 0; mf < 8; mf++)
#pragma unroll
                for (int nf = 0; nf < 4; nf++)
                    acc[mf][nf] = __builtin_amdgcn_mfma_f32_16x16x32_bf16(a[mf], bfr[nf], acc[mf][nf], 0, 0, 0);
        }
        __syncthreads();
    }

    float s[4];
#pragma unroll
    for (int nf = 0; nf < 4; nf++) {
        float bias = b2[wn * 64 + nf * 16 + l15];
        float v = 0.f;
#pragma unroll
        for (int mf = 0; mf < 8; mf++)
#pragma unroll
            for (int j = 0; j < 4; j++)
                v += fmaxf(acc[mf][nf][j] + bias, 0.f);
        v += __shfl_xor(v, 16, 64);
        v += __shfl_xor(v, 32, 64);
        s[nf] = v;
    }

    float* red = (float*)halo;
    if (lq == 0) {
#pragma unroll
        for (int nf = 0; nf < 4; nf++)
            red[((wm * 2 + wn) * 4 + nf) * 16 + l15] = s[nf];
    }
    __syncthreads();
    if (tid < 128) {
        int oc = tid;
        int wn2 = oc >> 6, nf2 = (oc >> 4) & 3, c16 = oc & 15;
        float tot = red[((0 * 2 + wn2) * 4 + nf2) * 16 + c16] +
                    red[((1 * 2 + wn2) * 4 + nf2) * 16 + c16];
        int bg = bglobal_base + bl;
        int tile = yt * 14 + xt;
        partial[((size_t)bg * 128 + oc) * 196 + tile] = tot;
    }
}

// ======== conv2 VARIANT B: 512 thr, 8 waves, M4N4 (acc=64 regs, fits 128-reg target). ========
// Wave (pm 0..3, pn 0..1): px rows [pm*4, pm*4+4) x 16 cols = 64 px, oc [pn*64, +64).
__global__ __launch_bounds__(512) void conv2_kernelB(const unsigned short* __restrict__ h1,
                                                     const unsigned short* __restrict__ w2bf,
                                                     const float* __restrict__ b2,
                                                     float* __restrict__ partial,
                                                     int bglobal_base)
{
    const int xt = blockIdx.x, yt = blockIdx.y, bl = blockIdx.z;
    const int x0 = xt * 16, y0 = yt * 16;
    const int tid = threadIdx.x;
    const int w = tid >> 6, lane = tid & 63;
    const int pm = w >> 1, pn = w & 1;
    const int l15 = lane & 15, lq = lane >> 4;

    __shared__ short halo[324 * 64];       // 41472 B
    __shared__ short wlds[2][128 * 64];    // 2x16384 B

    const unsigned short* hb = h1 + (size_t)bl * HH * WW * 64;

#pragma unroll
    for (int it = 0; it < 2; ++it) {
        int cbase = it * 512 + w * 64;
        int c = cbase + lane;
        int src = (c * 16) ^ (((c >> 3) & 7) << 4);
        gload_lds16((const char*)w2bf + src, (char*)&wlds[0][0] + cbase * 16);
    }

    for (int i = tid; i < 2592; i += 512) {
        int pos = i >> 3, q = i & 7;
        int row = pos / 18, col = pos - row * 18;
        int gy = y0 + row - 1, gx = x0 + col - 1;
        u32x4 v = {0, 0, 0, 0};
        if (gy >= 0 && gy < HH && gx >= 0 && gx < WW)
            v = *(const u32x4*)(hb + ((gy * WW + gx) * 64 + q * 8));
        int byte = (pos * 128 + q * 16) ^ ((pos & 7) << 4);
        *(u32x4*)((char*)halo + byte) = v;
    }
    __syncthreads();

    f32x4 acc[4][4];
#pragma unroll
    for (int mf = 0; mf < 4; mf++)
#pragma unroll
        for (int nf = 0; nf < 4; nf++)
            acc[mf][nf] = (f32x4){0.f, 0.f, 0.f, 0.f};

#pragma unroll
    for (int t = 0; t < 9; ++t) {
        if (t < 8) {
#pragma unroll
            for (int it = 0; it < 2; ++it) {
                int cbase = it * 512 + w * 64;
                int c = cbase + lane;
                int src = (c * 16) ^ (((c >> 3) & 7) << 4);
                gload_lds16((const char*)w2bf + (t + 1) * 16384 + src,
                            (char*)&wlds[(t + 1) & 1][0] + cbase * 16);
            }
        }
        const int dy = t / 3, dx = t % 3;
        const char* wbuf = (const char*)&wlds[t & 1][0];

#pragma unroll
        for (int kk = 0; kk < 2; kk++) {
            short8 bfr[4];
#pragma unroll
            for (int nf = 0; nf < 4; nf++) {
                int oc = pn * 64 + nf * 16 + l15;
                int byte = (oc * 128 + kk * 64 + lq * 16) ^ ((oc & 7) << 4);
                bfr[nf] = *(const short8*)(wbuf + byte);
            }
            short8 a[4];
#pragma unroll
            for (int mf = 0; mf < 4; mf++) {
                int pos = (pm * 4 + mf + dy) * 18 + (l15 + dx);
                int byte = (pos * 128 + kk * 64 + lq * 16) ^ ((pos & 7) << 4);
                a[mf] = *(const short8*)((const char*)halo + byte);
            }
#pragma unroll
            for (int mf = 0; mf < 4; mf++)
#pragma unroll
                for (int nf = 0; nf < 4; nf++)
                    acc[mf][nf] = __builtin_amdgcn_mfma_f32_16x16x32_bf16(a[mf], bfr[nf], acc[mf][nf], 0, 0, 0);
        }
        __syncthreads();
    }

    float s[4];
#pragma unroll
    for (int nf = 0; nf < 4; nf++) {
        float bias = b2[pn * 64 + nf * 16 + l15];
        float v = 0.f;
#pragma unroll
        for (int mf = 0; mf < 4; mf++)
#pragma unroll
            for (int j = 0; j < 4; j++)
                v += fmaxf(acc[mf][nf][j] + bias, 0.f);
        v += __shfl_xor(v, 16, 64);
        v += __shfl_xor(v, 32, 64);
        s[nf] = v;
    }

    float* red = (float*)halo;     // [pm 4][pn 2][nf 4][16] = 512 floats
    __syncthreads();
    if (lq == 0) {
#pragma unroll
        for (int nf = 0; nf < 4; nf++)
            red[((pm * 2 + pn) * 4 + nf) * 16 + l15] = s[nf];
    }
    __syncthreads();
    if (tid < 128) {
        int oc = tid;
        int pn2 = oc >> 6, nf2 = (oc >> 4) & 3, c16 = oc & 15;
        float tot = 0.f;
#pragma unroll
        for (int pm2 = 0; pm2 < 4; pm2++)
            tot += red[((pm2 * 2 + pn2) * 4 + nf2) * 16 + c16];
        int bg = bglobal_base + bl;
        int tile = yt * 14 + xt;
        partial[((size_t)bg * 128 + oc) * 196 + tile] = tot;
    }
}

// ---------------- feats: sum 196 tile-partials -> mean ----------------
__global__ void feats_reduce(const float* __restrict__ partial, float* __restrict__ out)
{
    int t = blockIdx.x;           // 0..4095 = b*128+oc
    int lane = threadIdx.x;       // 64
    float s = 0.f;
    for (int k = lane; k < 196; k += 64) s += partial[(size_t)t * 196 + k];
#pragma unroll
    for (int m = 32; m >= 1; m >>= 1) s += __shfl_xor(s, m, 64);
    if (lane == 0) out[t] = s * (1.f / 50176.f);
}

// ---------------- NMS: one block per batch (exact reference semantics) ----------------
__global__ __launch_bounds__(128) void nms_kernel(const float* __restrict__ boxes,
                                                  const float* __restrict__ scores,
                                                  float* __restrict__ out)
{
    const int b = blockIdx.x;
    const int tid = threadIdx.x;
    __shared__ float rs[100];
    __shared__ float bx1[100], by1[100], bx2[100], by2[100];
    __shared__ float ss[100], sx1[100], sy1[100], sx2[100], sy2[100], sarea[100];
    __shared__ int keep_s[100];

    if (tid < 100) {
        rs[tid] = scores[b * 100 + tid];
        bx1[tid] = boxes[(b * 100 + tid) * 4 + 0];
        by1[tid] = boxes[(b * 100 + tid) * 4 + 1];
        bx2[tid] = boxes[(b * 100 + tid) * 4 + 2];
        by2[tid] = boxes[(b * 100 + tid) * 4 + 3];
    }
    __syncthreads();
    if (tid < 100) {
        float s = rs[tid];
        int r = 0;
        for (int j = 0; j < 100; j++) {
            float sj = rs[j];
            r += (sj > s) || (sj == s && j < tid);  // stable descending rank
        }
        ss[r] = s; sx1[r] = bx1[tid]; sy1[r] = by1[tid];
        sx2[r] = bx2[tid]; sy2[r] = by2[tid];
        keep_s[tid] = 1;
    }
    __syncthreads();
    if (tid < 100)
        sarea[tid] = fmaxf(sx2[tid] - sx1[tid], 0.f) * fmaxf(sy2[tid] - sy1[tid], 0.f);
    __syncthreads();

    for (int i = 0; i < 99; i++) {
        if (keep_s[i] && tid > i && tid < 100) {
            float xx1 = fmaxf(sx1[i], sx1[tid]);
            float yy1 = fmaxf(sy1[i], sy1[tid]);
            float xx2 = fminf(sx2[i], sx2[tid]);
            float yy2 = fminf(sy2[i], sy2[tid]);
            float inter = fmaxf(xx2 - xx1, 0.f) * fmaxf(yy2 - yy1, 0.f);
            float iou = inter / (sarea[i] + sarea[tid] - inter + 1e-9f);
            if (iou > 0.5f) keep_s[tid] = 0;
        }
        __syncthreads();
    }

    if (tid < 100) {
        int k = keep_s[tid];
        int gi = b * 100 + tid;
        out[OUT_BOXES + gi * 4 + 0] = k ? sx1[tid] : 0.f;
        out[OUT_BOXES + gi * 4 + 1] = k ? sy1[tid] : 0.f;
        out[OUT_BOXES + gi * 4 + 2] = k ? sx2[tid] : 0.f;
        out[OUT_BOXES + gi * 4 + 3] = k ? sy2[tid] : 0.f;
        out[OUT_SCORES + gi] = k ? ss[tid] : 0.f;
        out[OUT_KEEP + gi] = k ? 1.f : 0.f;
    }
}

extern "C" void kernel_launch(void* const* d_in, const int* in_sizes, int n_in,
                              void* d_out, int out_size, void* d_ws, size_t ws_size,
                              hipStream_t stream)
{
    const float* x      = (const float*)d_in[0];
    const float* boxes  = (const float*)d_in[1];
    const float* scores = (const float*)d_in[2];
    const float* w1     = (const float*)d_in[3];
    const float* b1     = (const float*)d_in[4];
    const float* w2     = (const float*)d_in[5];
    const float* b2     = (const float*)d_in[6];
    float* out = (float*)d_out;

    // ws: h1 slice (8 batches NHWC bf16, 51.38 MB) | w2bf (147 KB) | w1bf (4 KB) | partial (3.2 MB)
    char* wsb = (char*)d_ws;
    unsigned short* h1   = (unsigned short*)wsb;
    unsigned short* w2bf = (unsigned short*)(wsb + (size_t)8 * 224 * 224 * 64 * 2);
    unsigned short* w1bf = (unsigned short*)(wsb + (size_t)8 * 224 * 224 * 64 * 2 + 9 * 128 * 64 * 2);
    float*          partial = (float*)(wsb + (size_t)8 * 224 * 224 * 64 * 2 + 9 * 128 * 64 * 2 + 64 * 32 * 2);

    w2_convert<<<(9 * 128 * 64 + 255) / 256, 256, 0, stream>>>(w2, w2bf);
    w1_convert<<<8, 256, 0, stream>>>(w1, w1bf);

    for (int s = 0; s < 4; s++) {
        const float* xs = x + (size_t)s * 8 * 3 * HH * WW;
        conv1_kernel<<<dim3(14, 14, 8), 256, 0, stream>>>(xs, w1bf, b1, h1);
        if ((s & 1) == 0)
            conv2_kernelA<<<dim3(14, 14, 8), 256, 0, stream>>>(h1, w2bf, b2, partial, s * 8);
        else
            conv2_kernelB<<<dim3(14, 14, 8), 512, 0, stream>>>(h1, w2bf, b2, partial, s * 8);
    }

    feats_reduce<<<4096, 64, 0, stream>>>(partial, out + OUT_FEATS);
    nms_kernel<<<32, 128, 0, stream>>>(boxes, scores, out);
}